// Round 1
// 684.693 us; speedup vs baseline: 1.0497x; 1.0497x over previous
//
#include <hip/hip_runtime.h>

typedef __bf16 bf16x8_t __attribute__((ext_vector_type(8)));
typedef float f32x4_t __attribute__((ext_vector_type(4)));
typedef float f32x2_t __attribute__((ext_vector_type(2)));

#define NSTEPS 100
#define PB0 0u          // partials double-buffer: [0,32K) and [32K,64K)
#define PB1 32768u
#define COMBF 51200u    // comb-input bf16 fragments at [51200, 63488) (post-loop only)

static __device__ __forceinline__ unsigned short f2bfu(float v) {
  union { __bf16 h; unsigned short u; } c; c.h = (__bf16)v; return c.u;  // RTNE
}
static __device__ __forceinline__ unsigned int pack2bf(float a, float b) {
  return (unsigned)f2bfu(a) | ((unsigned)f2bfu(b) << 16);
}
union BF8U { unsigned int u[4]; bf16x8_t v; };

// VOP3P packed fp32 (gfx90a+, present on gfx950): elementwise IEEE mul/add on a
// VGPR pair. Per-half bitwise-identical to v_mul_f32/v_add_f32 -> exactness kept.
static __device__ __forceinline__ f32x2_t pk_mul(f32x2_t a, f32x2_t b) {
  f32x2_t d; asm("v_pk_mul_f32 %0, %1, %2" : "=v"(d) : "v"(a), "v"(b)); return d;
}
static __device__ __forceinline__ f32x2_t pk_add(f32x2_t a, f32x2_t b) {
  f32x2_t d; asm("v_pk_add_f32 %0, %1, %2" : "=v"(d) : "v"(a), "v"(b)); return d;
}

static __device__ __forceinline__ bf16x8_t bfrag_f32(const float* __restrict__ p, float s) {
  BF8U r;
#pragma unroll
  for (int i = 0; i < 4; ++i) r.u[i] = pack2bf(p[2*i]*s, p[2*i+1]*s);
  return r.v;
}

static __device__ __forceinline__ void comb_store(unsigned char* ldsp, int k, int row, float v) {
  *(unsigned short*)(ldsp + COMBF +
      (unsigned)((k >> 5)*1024 + (((k >> 3) & 3)*16 + row)*16 + (k & 7)*2)) = f2bfu(v);
}

// 512 threads = 8 waves = 2 waves/SIMD -> 256-reg unified budget.
// ~225 regs used (mem2/c2/spneg2 pairs + 64 bfr + afr): still 2 waves/SIMD, no spill.
__global__ __launch_bounds__(512, 2)
void hybrid_v5(const float* __restrict__ x,
               const float* __restrict__ snn_w1, const float* __restrict__ snn_b1,
               const float* __restrict__ snn_w2, const float* __restrict__ snn_b2,
               const float* __restrict__ nn_w1,  const float* __restrict__ nn_b1,
               const float* __restrict__ nn_w2,  const float* __restrict__ nn_b2,
               const float* __restrict__ conv_w, const float* __restrict__ conv_b,
               const float* __restrict__ fc_w,   const float* __restrict__ fc_b,
               const float* __restrict__ comb_w, const float* __restrict__ comb_b,
               const unsigned short* __restrict__ fcwb, int use_bf,
               float* __restrict__ out)
{
  __shared__ __align__(16) unsigned char lds[65536];
  const int tid  = threadIdx.x;
  const int w    = tid >> 6;        // wave 0..7: K-slice [128w, 128w+128)
  const int l    = tid & 63;
  const int q    = l >> 4;
  const int m    = l & 15;
  const int row0 = blockIdx.x * 16;

  const int hi  = w >> 2;
  const int ntr = w & 3;
  const int rn  = ntr*16 + m;       // owned output col 0..63
  const int rA  = hi*4 + q;         // owned row A 0..7 (row B = rA+8)

  const float* xr = x + (row0 + m)*105;
  const float f0 = xr[0], f1 = xr[1], f2 = xr[2], f3 = xr[3], f4 = xr[4];
  const float b2l = snn_b2[rn];

  // resident snn_w2 B-fragments: 4 k-chunks x 4 n-tiles (64 regs, AGPR-eligible)
  bf16x8_t bfr[4][4];
#pragma unroll
  for (int ci = 0; ci < 4; ++ci)
#pragma unroll
    for (int nt = 0; nt < 4; ++nt)
      bfr[ci][nt] = bfrag_f32(snn_w2 + (nt*16 + m)*1024 + (w*4 + ci)*32 + q*8, 1.f);

  // layer-1 LIF state: lane's 32 A-fragment cells, packed as 16 f32 pairs.
  // spneg2 holds spikes as {-1.0f or -0.0f}: x + (-sp) is bit-identical to x - sp,
  // and removes the per-step re-compare (spike reused from last step's compare).
  f32x2_t c2[16], mem2[16], spneg2[16];
  f32x2_t beta2; beta2.x = 0.95f; beta2.y = 0.95f;
  {
    const int kb = w*128 + q*8;
#pragma unroll
    for (int ci = 0; ci < 4; ++ci) {
      const float* wp = snn_w1 + (kb + ci*32)*5;
      float wa[40];
#pragma unroll
      for (int u2 = 0; u2 < 10; ++u2) {
        const float4 t4 = *(const float4*)(wp + u2*4);
        wa[u2*4+0] = t4.x; wa[u2*4+1] = t4.y; wa[u2*4+2] = t4.z; wa[u2*4+3] = t4.w;
      }
      float cc[8];
#pragma unroll
      for (int j = 0; j < 8; ++j)
        cc[j] = f0*wa[j*5] + f1*wa[j*5+1] + f2*wa[j*5+2] + f3*wa[j*5+3] + f4*wa[j*5+4]
              + snn_b1[kb + ci*32 + j];
#pragma unroll
      for (int jj = 0; jj < 4; ++jj) {
        f32x2_t t; t.x = cc[2*jj]; t.y = cc[2*jj+1];
        c2[ci*4+jj] = t;
        f32x2_t z; z.x = 0.f; z.y = 0.f;
        mem2[ci*4+jj] = z;
        f32x2_t nz; nz.x = -0.0f; nz.y = -0.0f;
        spneg2[ci*4+jj] = nz;
      }
    }
  }

  BF8U afr[4];
  // mem = (0.95*mem + c) + (-sp)  [bit-exact np order: mul, add, add(-sp)]
  // afr word from spneg pair: perm picks hi16 of each (0xBF80 / 0x8000),
  // & 0x3F803F80 clears the sign -> packed bf16 {1.0, 0.0}. 2 instr/word vs 5.
  auto lif_update_pack = [&]() {
#pragma unroll
    for (int i = 0; i < 16; ++i) {
      const f32x2_t mk = pk_add(pk_add(pk_mul(mem2[i], beta2), c2[i]), spneg2[i]);
      mem2[i] = mk;
      f32x2_t sn;
      sn.x = mk.x > 1.f ? -1.0f : -0.0f;
      sn.y = mk.y > 1.f ? -1.0f : -0.0f;
      spneg2[i] = sn;
      afr[i>>2].u[i&3] =
          __builtin_amdgcn_perm(__float_as_uint(sn.y), __float_as_uint(sn.x), 0x07060302u)
          & 0x3F803F80u;
    }
  };
  lif_update_pack();                 // spikes(t=0) in registers

  // layer-2 LIF state, packed {rowA, rowB}; counts accumulated negative.
  f32x2_t m2;     m2.x = 0.f;     m2.y = 0.f;
  f32x2_t s2neg;  s2neg.x = -0.0f; s2neg.y = -0.0f;
  f32x2_t cntneg; cntneg.x = 0.f; cntneg.y = 0.f;
  f32x2_t sbias2; sbias2.x = b2l; sbias2.y = b2l;

  // paired-partials layout: [wave][row%8][col][row/8] f32.
  // write: 16x ds_write_b32 off one base (2-way bank alias = free);
  // read: rows (rA, rA+8) adjacent -> 8x ds_read_b64 lands {vA,vB} in pairs.
  const unsigned wbase = (unsigned)(w*4096 + (q&1)*2048 + (q>>1)*4 + m*8);
  const unsigned rbase = (unsigned)(rA*512 + rn*8);
  const f32x4_t z4 = {0.f, 0.f, 0.f, 0.f};

  auto lif2 = [&](f32x2_t cur2) {
    m2 = pk_add(pk_add(pk_mul(m2, beta2), cur2), s2neg);
    f32x2_t sn;
    sn.x = m2.x > 1.f ? -1.0f : -0.0f;
    sn.y = m2.y > 1.f ? -1.0f : -0.0f;
    s2neg = sn;
    cntneg = pk_add(cntneg, sn);
  };

  // one phase: reads(t-1) | MFMA(t)+writes | LIF(t+1) | reduce(t-1)
  auto phase = [&](unsigned cur, unsigned prv, bool doRead, bool doLif) {
    f32x2_t v2[8];
    if (doRead)
#pragma unroll
      for (int s = 0; s < 8; ++s)
        v2[s] = *(const f32x2_t*)(lds + prv + rbase + (unsigned)(s*4096));
    f32x4_t acc[4] = {z4, z4, z4, z4};
#pragma unroll
    for (int ci = 0; ci < 4; ++ci)
#pragma unroll
      for (int nt = 0; nt < 4; ++nt)
        acc[nt] = __builtin_amdgcn_mfma_f32_16x16x32_bf16(afr[ci].v, bfr[ci][nt], acc[nt], 0,0,0);
#pragma unroll
    for (int nt = 0; nt < 4; ++nt)
#pragma unroll
      for (int r = 0; r < 4; ++r)
        *(float*)(lds + cur + wbase + (unsigned)(r*512 + nt*128)) = acc[nt][r];
    if (doLif) lif_update_pack();
    if (doRead) {
      // exact same per-element tree shape as before: ((0+1)+(2+3))+((4+5)+(6+7)), then +bias
      const f32x2_t t = pk_add(pk_add(pk_add(v2[0],v2[1]), pk_add(v2[2],v2[3])),
                               pk_add(pk_add(v2[4],v2[5]), pk_add(v2[6],v2[7])));
      lif2(pk_add(t, sbias2));
    }
    __syncthreads();
  };

#pragma unroll 1
  for (int tt = 0; tt < NSTEPS; tt += 2) {
    phase(PB0, PB1, tt > 0, true);                 // t = tt   (even)
    phase(PB1, PB0, true,  tt + 1 < NSTEPS - 1);   // t = tt+1 (odd)
  }
  // partials(99) sit in PB1; reduced below, folded into the NN phase.

  // ============ NN branch + final SNN reduce (reads PB1, writes PB0) ============
#pragma unroll
  for (int ci = 0; ci < 4; ++ci)
#pragma unroll
    for (int nt = 0; nt < 4; ++nt)
      bfr[ci][nt] = bfrag_f32(nn_w2 + (nt*16 + m)*1024 + (w*4 + ci)*32 + q*8, 1.f);
  {
    // final SNN reduce (t = 99)
    f32x2_t v2[8];
#pragma unroll
    for (int s = 0; s < 8; ++s)
      v2[s] = *(const f32x2_t*)(lds + PB1 + rbase + (unsigned)(s*4096));
    const f32x2_t t = pk_add(pk_add(pk_add(v2[0],v2[1]), pk_add(v2[2],v2[3])),
                             pk_add(pk_add(v2[4],v2[5]), pk_add(v2[6],v2[7])));
    lif2(pk_add(t, sbias2));

    // NN hidden + MFMA
    BF8U hfr[4];
    const int kb = w*128 + q*8;
#pragma unroll
    for (int ci = 0; ci < 4; ++ci) {
      const float* wp = nn_w1 + (kb + ci*32)*5;
      float wa[40];
#pragma unroll
      for (int u2 = 0; u2 < 10; ++u2) {
        const float4 t4 = *(const float4*)(wp + u2*4);
        wa[u2*4+0] = t4.x; wa[u2*4+1] = t4.y; wa[u2*4+2] = t4.z; wa[u2*4+3] = t4.w;
      }
      float hv[8];
#pragma unroll
      for (int j = 0; j < 8; ++j) {
        const float h = f0*wa[j*5] + f1*wa[j*5+1] + f2*wa[j*5+2] + f3*wa[j*5+3] + f4*wa[j*5+4]
                      + nn_b1[kb + ci*32 + j];
        hv[j] = fmaxf(h, 0.f);
      }
#pragma unroll
      for (int jj = 0; jj < 4; ++jj) hfr[ci].u[jj] = pack2bf(hv[2*jj], hv[2*jj+1]);
    }
    f32x4_t acc[4] = {z4, z4, z4, z4};
#pragma unroll
    for (int ci = 0; ci < 4; ++ci)
#pragma unroll
      for (int nt = 0; nt < 4; ++nt)
        acc[nt] = __builtin_amdgcn_mfma_f32_16x16x32_bf16(hfr[ci].v, bfr[ci][nt], acc[nt], 0,0,0);
#pragma unroll
    for (int nt = 0; nt < 4; ++nt)
#pragma unroll
      for (int r = 0; r < 4; ++r)
        *(float*)(lds + PB0 + wbase + (unsigned)(r*512 + nt*128)) = acc[nt][r];
  }
  __syncthreads();
  {
    f32x2_t v2[8];
#pragma unroll
    for (int s = 0; s < 8; ++s)
      v2[s] = *(const f32x2_t*)(lds + PB0 + rbase + (unsigned)(s*4096));
    const f32x2_t t = pk_add(pk_add(pk_add(v2[0],v2[1]), pk_add(v2[2],v2[3])),
                             pk_add(pk_add(v2[4],v2[5]), pk_add(v2[6],v2[7])));
    const float nb = nn_b2[rn];
    f32x2_t nb2; nb2.x = nb; nb2.y = nb;
    const f32x2_t n2 = pk_add(t, nb2);
    // cnt = -cntneg (integer-valued): x * -0.0078125f is bit-identical to (-x)*0.0078125f
    comb_store(lds, rn,      rA,     cntneg.x * -0.0078125f);
    comb_store(lds, rn,      rA + 8, cntneg.y * -0.0078125f);
    comb_store(lds, 64 + rn, rA,     n2.x);
    comb_store(lds, 64 + rn, rA + 8, n2.y);
  }
  __syncthreads();

  // ======= CNN conv + relu + pairwise maxpool -> pooled bf16 frags [0,51200) =======
  {
    const int ch = tid >> 4;          // 0..31  (row = m)
    const float cw0 = conv_w[ch*3+0], cw1 = conv_w[ch*3+1], cw2 = conv_w[ch*3+2];
    const float cbb = conv_b[ch];
    const float* xw = xr + 5;
    float xm1 = 0.f, x0v = xw[0];
#pragma unroll 1
    for (int p = 0; p < 50; ++p) {
      const float xp1 = xw[2*p + 1];
      const float xp2 = (p < 49) ? xw[2*p + 2] : 0.f;
      const float av = cw0*xm1 + cw1*x0v + cw2*xp1 + cbb;
      const float bv = cw0*x0v + cw1*xp1 + cw2*xp2 + cbb;
      const float pv = fmaxf(fmaxf(av, 0.f), fmaxf(bv, 0.f));
      const int k = ch*50 + p;
      *(unsigned short*)(lds + (unsigned)((k>>5)*1024 + (((k>>3)&3)*16 + m)*16 + (k&7)*2)) = f2bfu(pv);
      xm1 = xp1; x0v = xp2;
    }
  }
  __syncthreads();

  // ================= CNN fc: wave w owns n-tiles {2w, 2w+1}, full K=1600 =================
  {
    const int c0 = (w*2 + 0)*16 + m;
    const int c1 = (w*2 + 1)*16 + m;
    f32x4_t e0 = z4, o0 = z4, e1 = z4, o1 = z4;
    if (use_bf) {
#pragma unroll 2
      for (int kc = 0; kc < 50; kc += 2) {
        const bf16x8_t a0 = *(const bf16x8_t*)(lds + (unsigned)((kc*64 + l)*16));
        const bf16x8_t a1 = *(const bf16x8_t*)(lds + (unsigned)(((kc+1)*64 + l)*16));
        e0 = __builtin_amdgcn_mfma_f32_16x16x32_bf16(a0, *(const bf16x8_t*)(fcwb + c0*1600 + kc*32 + q*8), e0, 0,0,0);
        o0 = __builtin_amdgcn_mfma_f32_16x16x32_bf16(a1, *(const bf16x8_t*)(fcwb + c0*1600 + (kc+1)*32 + q*8), o0, 0,0,0);
        e1 = __builtin_amdgcn_mfma_f32_16x16x32_bf16(a0, *(const bf16x8_t*)(fcwb + c1*1600 + kc*32 + q*8), e1, 0,0,0);
        o1 = __builtin_amdgcn_mfma_f32_16x16x32_bf16(a1, *(const bf16x8_t*)(fcwb + c1*1600 + (kc+1)*32 + q*8), o1, 0,0,0);
      }
    } else {
#pragma unroll 2
      for (int kc = 0; kc < 50; kc += 2) {
        const bf16x8_t a0 = *(const bf16x8_t*)(lds + (unsigned)((kc*64 + l)*16));
        const bf16x8_t a1 = *(const bf16x8_t*)(lds + (unsigned)(((kc+1)*64 + l)*16));
        e0 = __builtin_amdgcn_mfma_f32_16x16x32_bf16(a0, bfrag_f32(fc_w + c0*1600 + kc*32 + q*8, 1.f), e0, 0,0,0);
        o0 = __builtin_amdgcn_mfma_f32_16x16x32_bf16(a1, bfrag_f32(fc_w + c0*1600 + (kc+1)*32 + q*8, 1.f), o0, 0,0,0);
        e1 = __builtin_amdgcn_mfma_f32_16x16x32_bf16(a0, bfrag_f32(fc_w + c1*1600 + kc*32 + q*8, 1.f), e1, 0,0,0);
        o1 = __builtin_amdgcn_mfma_f32_16x16x32_bf16(a1, bfrag_f32(fc_w + c1*1600 + (kc+1)*32 + q*8, 1.f), o1, 0,0,0);
      }
    }
    const float fb0 = fc_b[c0], fb1 = fc_b[c1];
#pragma unroll
    for (int r = 0; r < 4; ++r) {
      comb_store(lds, 128 + c0, q*4 + r, (e0[r] + o0[r]) + fb0);
      comb_store(lds, 128 + c1, q*4 + r, (e1[r] + o1[r]) + fb1);
    }
  }
  __syncthreads();

  // ================= comb matmul: waves 0..3, wave w owns n-tile w, full K=384 =================
  if (w < 4) {
    const int cn = w*16 + m;
    f32x4_t oe = z4, oo = z4;
#pragma unroll
    for (int kc = 0; kc < 12; kc += 2) {
      const bf16x8_t a0 = *(const bf16x8_t*)(lds + COMBF + (unsigned)((kc*64 + l)*16));
      const bf16x8_t a1 = *(const bf16x8_t*)(lds + COMBF + (unsigned)(((kc+1)*64 + l)*16));
      const float s0 = (kc    < 2) ? 1.28f : 1.f;   // undo /128 on snn counts -> /100
      const float s1 = (kc+1 < 2) ? 1.28f : 1.f;
      oe = __builtin_amdgcn_mfma_f32_16x16x32_bf16(a0, bfrag_f32(comb_w + cn*384 + kc*32 + q*8, s0), oe, 0,0,0);
      oo = __builtin_amdgcn_mfma_f32_16x16x32_bf16(a1, bfrag_f32(comb_w + cn*384 + (kc+1)*32 + q*8, s1), oo, 0,0,0);
    }
    const float cb2 = comb_b[cn];
#pragma unroll
    for (int r = 0; r < 4; ++r)
      out[(row0 + q*4 + r)*64 + cn] = (oe[r] + oo[r]) + cb2;
  }
}

// fc_w fp32 -> bf16 (runs every call; d_ws is re-poisoned by the harness)
__global__ __launch_bounds__(256)
void fcw_to_bf16(const float* __restrict__ src, unsigned short* __restrict__ dst) {
  const int i = (blockIdx.x * 256 + threadIdx.x) * 4;
  const float4 v = *(const float4*)(src + i);
  ushort4 o;
  o.x = f2bfu(v.x); o.y = f2bfu(v.y); o.z = f2bfu(v.z); o.w = f2bfu(v.w);
  *(ushort4*)(dst + i) = o;
}

extern "C" void kernel_launch(void* const* d_in, const int* in_sizes, int n_in,
                              void* d_out, int out_size, void* d_ws, size_t ws_size,
                              hipStream_t stream) {
  const float* x       = (const float*)d_in[0];
  const float* snn_w1  = (const float*)d_in[1];
  const float* snn_b1  = (const float*)d_in[2];
  const float* snn_w2  = (const float*)d_in[3];
  const float* snn_b2  = (const float*)d_in[4];
  const float* nn_w1   = (const float*)d_in[5];
  const float* nn_b1   = (const float*)d_in[6];
  const float* nn_w2   = (const float*)d_in[7];
  const float* nn_b2   = (const float*)d_in[8];
  const float* conv_w  = (const float*)d_in[9];
  const float* conv_b  = (const float*)d_in[10];
  const float* fc_w    = (const float*)d_in[11];
  const float* fc_b    = (const float*)d_in[12];
  const float* comb_w  = (const float*)d_in[13];
  const float* comb_b  = (const float*)d_in[14];
  float* outp = (float*)d_out;

  const int rows = in_sizes[0] / 105;          // 16384
  const int grid = rows / 16;                  // 1024

  const size_t fcw_elems = (size_t)in_sizes[11];          // 256*1600 = 409600
  const int use_bf = (ws_size >= fcw_elems * 2) ? 1 : 0;
  unsigned short* fcwb = (unsigned short*)d_ws;
  if (use_bf) {
    fcw_to_bf16<<<dim3((unsigned)(fcw_elems / 1024)), dim3(256), 0, stream>>>(fc_w, fcwb);
  }

  hybrid_v5<<<dim3(grid), dim3(512), 0, stream>>>(
      x, snn_w1, snn_b1, snn_w2, snn_b2,
      nn_w1, nn_b1, nn_w2, nn_b2,
      conv_w, conv_b, fc_w, fc_b, comb_w, comb_b,
      fcwb, use_bf, outp);
}